// Round 6
// baseline (926.667 us; speedup 1.0000x reference)
//
#include <hip/hip_runtime.h>
#include <hip/hip_cooperative_groups.h>
#include <math.h>

namespace cg = cooperative_groups;

#define N_NODES 50000
#define N_EDGES 800000
#define HEADS 4
#define HID 64
#define FDIM 256      // HEADS*HID == F_IN == 256 for both layers
#define LDA 40        // padded LDS k-stride (halves): 80B row stride
#define SCAN_CHUNK 1024
#define SCAN_NB ((N_NODES + SCAN_CHUNK - 1) / SCAN_CHUNK)   // 49
#define COOP_BLOCKS 1024

typedef __attribute__((ext_vector_type(8))) _Float16 half8;
typedef __attribute__((ext_vector_type(4))) _Float16 half4;
typedef __attribute__((ext_vector_type(4))) float f32x4;

// ---------------------------------------------------- fused prep + CSR build
// ONE cooperative kernel replaces: memset, wcast, hist, scan_local,
// scan_bsum, scan_add, scatter (7 dispatches -> 1). Rationale: ~10us launch
// overhead per dispatch dominated the timeline (measured: 12 dispatches,
// ~130us unaccounted by per-kernel durations). Phases separated by
// grid.sync(); 1024 blocks x 256 threads (4 blocks/CU, co-resident).
__global__ __launch_bounds__(256) void build_all(const int* __restrict__ src,
                                                 const int* __restrict__ dst,
                                                 const float* __restrict__ W0,
                                                 const float* __restrict__ W1,
                                                 _Float16* __restrict__ wt0,
                                                 _Float16* __restrict__ wt1,
                                                 int* __restrict__ counts,
                                                 int* __restrict__ cursor,
                                                 int* __restrict__ offs,
                                                 int* __restrict__ bsum,
                                                 int* __restrict__ csr_src) {
    cg::grid_group grid = cg::this_grid();
    const int b = blockIdx.x, tt = threadIdx.x;
    const int t = b * 256 + tt;
    const int NT = gridDim.x * 256;
    __shared__ int part[256];

    // ---- phase A: zero counts/cursor + W transpose-cast (independent work)
    for (int i = t; i < N_NODES; i += NT) { counts[i] = 0; cursor[i] = 0; }
    for (int i = t; i < 2 * FDIM * FDIM; i += NT) {
        int which = i >> 16;          // 65536 elements per matrix
        int rem = i & 65535;
        int n = rem >> 8, k = rem & 255;
        const float* W = which ? W1 : W0;
        _Float16* wt = which ? wt1 : wt0;
        wt[n * FDIM + k] = (_Float16)W[k * FDIM + n];
    }
    grid.sync();

    // ---- phase B: histogram of dst
    for (int i = t; i < N_EDGES; i += NT) atomicAdd(&counts[dst[i]], 1);
    grid.sync();

    // ---- phase C: per-block chunk scan (first SCAN_NB blocks)
    const int base = b * SCAN_CHUNK + tt * 4;
    int s0_ = 0, s1_ = 0, s2_ = 0, s3_ = 0;
    if (b < SCAN_NB) {
        int v[4];
#pragma unroll
        for (int j = 0; j < 4; j++) {
            int idx = base + j;
            v[j] = (idx < N_NODES) ? counts[idx] : 0;
        }
        s0_ = v[0]; s1_ = s0_ + v[1]; s2_ = s1_ + v[2]; s3_ = s2_ + v[3];
        part[tt] = s3_;
        __syncthreads();
        for (int off = 1; off < 256; off <<= 1) {
            int x = (tt >= off) ? part[tt - off] : 0;
            __syncthreads();
            part[tt] += x;
            __syncthreads();
        }
        int prefix = (tt > 0) ? part[tt - 1] : 0;
        int ev[4] = {prefix, prefix + s0_, prefix + s1_, prefix + s2_};
#pragma unroll
        for (int j = 0; j < 4; j++) {
            int idx = base + j;
            if (idx < N_NODES) offs[idx] = ev[j];
        }
        if (tt == 255) bsum[b] = part[255];
    }
    grid.sync();

    // ---- phase D: single-wave scan of block sums
    if (b == 0 && tt < 64) {
        int lane = tt;
        int own = (lane < SCAN_NB) ? bsum[lane] : 0;
        int v = own;
        for (int off = 1; off < 64; off <<= 1) {
            int x = __shfl_up(v, off);
            if (lane >= off) v += x;
        }
        if (lane < SCAN_NB) bsum[lane] = v - own;   // exclusive prefix
        if (lane == SCAN_NB - 1) offs[N_NODES] = v; // grand total
    }
    grid.sync();

    // ---- phase E: add block prefix
    if (b < SCAN_NB) {
        int p = bsum[b];
#pragma unroll
        for (int j = 0; j < 4; j++) {
            int idx = base + j;
            if (idx < N_NODES) offs[idx] += p;
        }
    }
    grid.sync();

    // ---- phase F: scatter edges into CSR
    for (int i = t; i < N_EDGES; i += NT) {
        int d = dst[i];
        int p = offs[d] + atomicAdd(&cursor[d], 1);
        csr_src[p] = src[i];
    }
}

// -------------------------------------------- fp16 MFMA GEMM + fused el/er
// v4: BN=256 (whole N in one block), 512 threads / 8 waves, each wave a
// 64x64 sub-tile (wr = (wave>>2)*64, wc = (wave&3)*64). A tile staged ONCE
// per block. Template A32: stage A directly from fp32 (layer 1 — no
// separate cast pass). el/er fused in the epilogue (wave's 64-col
// quadrant == head).
template <int A32>
__global__ __launch_bounds__(512) void mfma_gemm(const _Float16* __restrict__ A16,
                                                 const float* __restrict__ Af,
                                                 const _Float16* __restrict__ Bt,
                                                 const float* __restrict__ al,
                                                 const float* __restrict__ ar,
                                                 _Float16* __restrict__ feat16,
                                                 float* __restrict__ el,
                                                 float* __restrict__ er) {
    __shared__ _Float16 ash[128][LDA];
    __shared__ _Float16 bsh[256][LDA];

    const int t = threadIdx.x;
    const int m0 = blockIdx.x * 128;
    const int wave = t >> 6, lane = t & 63;
    const int quad = lane >> 4, l16 = lane & 15;
    const int wr = (wave >> 2) * 64;
    const int wc = (wave & 3) * 64;

    const f32x4 zero = {0.f, 0.f, 0.f, 0.f};
    f32x4 acc[4][4];
#pragma unroll
    for (int i = 0; i < 4; i++)
#pragma unroll
        for (int j = 0; j < 4; j++) acc[i][j] = zero;

    for (int kk = 0; kk < FDIM; kk += 32) {
        // ---- stage A: 128 rows x 32 halves = 512 x 8-half chunks, 1/thread
        {
            int row = t >> 2;
            int kb = (t & 3) * 8;
            int gr = m0 + row; if (gr >= N_NODES) gr = N_NODES - 1;
            if (A32) {
                const float* p = &Af[(size_t)gr * FDIM + kk + kb];
                float4 f0 = *(const float4*)p;
                float4 f1 = *(const float4*)(p + 4);
                half8 hv = {(_Float16)f0.x, (_Float16)f0.y, (_Float16)f0.z, (_Float16)f0.w,
                            (_Float16)f1.x, (_Float16)f1.y, (_Float16)f1.z, (_Float16)f1.w};
                *(half8*)&ash[row][kb] = hv;
            } else {
                *(half8*)&ash[row][kb] = *(const half8*)&A16[(size_t)gr * FDIM + kk + kb];
            }
        }
        // ---- stage B: 256 rows x 32 halves = 1024 chunks, 2/thread
#pragma unroll
        for (int ii = 0; ii < 2; ii++) {
            int idx = t + ii * 512;
            int row = idx >> 2;
            int kb = (idx & 3) * 8;
            *(half8*)&bsh[row][kb] = *(const half8*)&Bt[(size_t)row * FDIM + kk + kb];
        }
        __syncthreads();

        half8 af[4], bf[4];
#pragma unroll
        for (int i = 0; i < 4; i++) {
            af[i] = *(half8*)&ash[wr + i * 16 + l16][quad * 8];
            bf[i] = *(half8*)&bsh[wc + i * 16 + l16][quad * 8];
        }
#pragma unroll
        for (int mt = 0; mt < 4; mt++)
#pragma unroll
            for (int nt = 0; nt < 4; nt++)
                acc[mt][nt] = __builtin_amdgcn_mfma_f32_16x16x32_f16(af[mt], bf[nt], acc[mt][nt], 0, 0, 0);
        __syncthreads();
    }

    // ---- epilogue: feat16 store + fused el/er (this wave's head = h)
    const int h = wc >> 6;
    float alv[4], arv[4];
#pragma unroll
    for (int nt = 0; nt < 4; nt++) {
        alv[nt] = al[wc + nt * 16 + l16];
        arv[nt] = ar[wc + nt * 16 + l16];
    }
#pragma unroll
    for (int mt = 0; mt < 4; mt++) {
        int m = m0 + wr + mt * 16 + quad * 4;
        float pl[4] = {0.f, 0.f, 0.f, 0.f}, pr[4] = {0.f, 0.f, 0.f, 0.f};
#pragma unroll
        for (int nt = 0; nt < 4; nt++) {
            int n = wc + nt * 16 + l16;
#pragma unroll
            for (int r = 0; r < 4; r++) {
                float v = acc[mt][nt][r];
                if (m + r < N_NODES) feat16[(size_t)(m + r) * FDIM + n] = (_Float16)v;
                pl[r] += v * alv[nt];
                pr[r] += v * arv[nt];
            }
        }
#pragma unroll
        for (int r = 0; r < 4; r++) {
            float a = pl[r], b = pr[r];
            for (int off = 8; off; off >>= 1) {
                a += __shfl_down(a, off, 16);
                b += __shfl_down(b, off, 16);
            }
            if (l16 == 0 && m + r < N_NODES) {
                el[(m + r) * 4 + h] = a;
                er[(m + r) * 4 + h] = b;
            }
        }
    }
}

// ------------------------------------------- fused softmax + aggregate
// Wave per node, NO LDS / NO barriers. Lane owns features f=lane*4..+3
// (head = lane>>4).
//
// v2 (best measured; traffic-bound at ~3.9 TB/s beyond-L2, invariant to
// scheduling — v3's deeper MLP regressed): cooperative weights. Edges
// walked in 16-chunks; W-phase: lane (lane&15)==j computes edge c+j's
// weight for its OWN head; MAC-phase broadcasts (s,w) via __shfl, 4-wide.
// Denominator accumulated per-lane, reduced once at the end.
// Single-pass softmax (no max subtraction — logits are O(1)).
// mode 0: write h1 as fp16 (layer-2 GEMM input, lives in d_out)
// mode 1: final fp32 head-major write
__global__ __launch_bounds__(256) void agg_fused(const _Float16* __restrict__ feat16,
                                                 const float* __restrict__ el,
                                                 const float* __restrict__ er,
                                                 const float* __restrict__ bias,
                                                 const int* __restrict__ offs,
                                                 const int* __restrict__ csr_src,
                                                 float* __restrict__ out,
                                                 _Float16* __restrict__ h1,
                                                 int mode) {
    const int wave = threadIdx.x >> 6;
    const int lane = threadIdx.x & 63;
    const int n = blockIdx.x * 4 + wave;
    const int head = lane >> 4;
    const int f = lane * 4;           // == head*64 + (lane&15)*4
    const int base16 = lane & 48;     // first lane of this head's 16-group
    const int j16 = lane & 15;
    const int beg = offs[n];
    const int end = offs[n + 1];
    const float er_h = er[n * 4 + head];

    float4 acc = make_float4(0.f, 0.f, 0.f, 0.f);
    float ss = 0.f;

    for (int c = beg; c < end; c += 16) {
        // ---- W-phase: this lane owns edge c + j16 (for its own head)
        int e = c + j16;
        int s_own = 0;
        float w_own = 0.f;
        if (e < end) {
            s_own = csr_src[e];
            float lg = el[s_own * 4 + head] + er_h;
            lg = (lg > 0.f) ? lg : 0.2f * lg;
            w_own = __expf(lg);
        }
        ss += w_own;

        int rem = end - c;
        if (rem > 16) rem = 16;

        // ---- MAC-phase: walk the chunk's edges, s/w via shuffle broadcast
        int j = 0;
        for (; j + 3 < rem; j += 4) {
            int s0 = __shfl(s_own, base16 + j);
            int s1 = __shfl(s_own, base16 + j + 1);
            int s2 = __shfl(s_own, base16 + j + 2);
            int s3 = __shfl(s_own, base16 + j + 3);
            float w0 = __shfl(w_own, base16 + j);
            float w1 = __shfl(w_own, base16 + j + 1);
            float w2 = __shfl(w_own, base16 + j + 2);
            float w3 = __shfl(w_own, base16 + j + 3);
            half4 v0 = *(const half4*)&feat16[(size_t)s0 * FDIM + f];
            half4 v1 = *(const half4*)&feat16[(size_t)s1 * FDIM + f];
            half4 v2 = *(const half4*)&feat16[(size_t)s2 * FDIM + f];
            half4 v3 = *(const half4*)&feat16[(size_t)s3 * FDIM + f];
            acc.x += w0 * (float)v0[0] + w1 * (float)v1[0];
            acc.y += w0 * (float)v0[1] + w1 * (float)v1[1];
            acc.z += w0 * (float)v0[2] + w1 * (float)v1[2];
            acc.w += w0 * (float)v0[3] + w1 * (float)v1[3];
            acc.x += w2 * (float)v2[0] + w3 * (float)v3[0];
            acc.y += w2 * (float)v2[1] + w3 * (float)v3[1];
            acc.z += w2 * (float)v2[2] + w3 * (float)v3[2];
            acc.w += w2 * (float)v2[3] + w3 * (float)v3[3];
        }
        for (; j < rem; j++) {
            int s0 = __shfl(s_own, base16 + j);
            float w0 = __shfl(w_own, base16 + j);
            half4 v0 = *(const half4*)&feat16[(size_t)s0 * FDIM + f];
            acc.x += w0 * (float)v0[0];
            acc.y += w0 * (float)v0[1];
            acc.z += w0 * (float)v0[2];
            acc.w += w0 * (float)v0[3];
        }
    }

    // ---- reduce softmax denominator across the 16-lane head group
    ss += __shfl_xor(ss, 1, 16);
    ss += __shfl_xor(ss, 2, 16);
    ss += __shfl_xor(ss, 4, 16);
    ss += __shfl_xor(ss, 8, 16);

    float S = fmaxf(ss, 1e-9f);
    float inv = 1.f / S;
    float4 bv = *(const float4*)&bias[f];
    float r0 = acc.x * inv + bv.x;
    float r1 = acc.y * inv + bv.y;
    float r2 = acc.z * inv + bv.z;
    float r3 = acc.w * inv + bv.w;
    r0 = (r0 > 0.f) ? r0 : expm1f(r0);
    r1 = (r1 > 0.f) ? r1 : expm1f(r1);
    r2 = (r2 > 0.f) ? r2 : expm1f(r2);
    r3 = (r3 > 0.f) ? r3 : expm1f(r3);

    if (mode) {
        const int d = (lane & 15) * 4;
        float4 rv = make_float4(r0, r1, r2, r3);
        *(float4*)&out[(size_t)head * N_NODES * HID + (size_t)n * HID + d] = rv;
    } else {
        half4 hv = {(_Float16)r0, (_Float16)r1, (_Float16)r2, (_Float16)r3};
        *(half4*)&h1[(size_t)n * FDIM + f] = hv;
    }
}

// ---------------------------------------------------------------- launch

extern "C" void kernel_launch(void* const* d_in, const int* in_sizes, int n_in,
                              void* d_out, int out_size, void* d_ws, size_t ws_size,
                              hipStream_t stream) {
    const float* x   = (const float*)d_in[0];
    const int*   src = (const int*)d_in[1];
    const int*   dst = (const int*)d_in[2];
    const float* W0  = (const float*)d_in[3];
    const float* al0 = (const float*)d_in[4];
    const float* ar0 = (const float*)d_in[5];
    const float* b0  = (const float*)d_in[6];
    const float* W1  = (const float*)d_in[7];
    const float* al1 = (const float*)d_in[8];
    const float* ar1 = (const float*)d_in[9];
    const float* b1  = (const float*)d_in[10];
    float* out = (float*)d_out;

    // h1 (layer-1 hidden, fp16) lives in the first 25.6 MB of d_out.
    // Timeline: gemm-1 reads x fp32 directly -> agg(mode0) writes h1 ->
    // gemm-2 reads h1 -> agg(mode1) overwrites all of d_out with the final
    // output. All sequential on stream.
    _Float16* h1 = (_Float16*)d_out;

    // workspace layout
    _Float16* feat16 = (_Float16*)d_ws;                          // N*256 fp16
    _Float16* wt0 = feat16 + (size_t)N_NODES * FDIM;             // 256*256
    _Float16* wt1 = wt0 + FDIM * FDIM;                           // 256*256
    float* el    = (float*)(wt1 + FDIM * FDIM);                  // N*4
    float* er    = el + N_NODES * HEADS;                         // N*4
    int* counts  = (int*)(er + N_NODES * HEADS);                 // N
    int* cursor  = counts + N_NODES;                             // N
    int* offs    = cursor + N_NODES;                             // N+1 (pad 50016)
    int* bsum    = offs + 50016;                                 // 64
    int* csr_src = bsum + 64;                                    // E

    // ---- fused prep + CSR build (1 cooperative dispatch, was 7)
    {
        void* args[] = {(void*)&src, (void*)&dst, (void*)&W0, (void*)&W1,
                        (void*)&wt0, (void*)&wt1, (void*)&counts, (void*)&cursor,
                        (void*)&offs, (void*)&bsum, (void*)&csr_src};
        hipLaunchCooperativeKernel((const void*)build_all, dim3(COOP_BLOCKS),
                                   dim3(256), args, 0, stream);
    }

    const int ggrid = (N_NODES + 127) / 128;   // 391

    // ---- layer 1 (A from fp32 x; h1 fp16 written into d_out)
    mfma_gemm<1><<<ggrid, 512, 0, stream>>>(nullptr, x, wt0, al0, ar0, feat16, el, er);
    agg_fused<<<N_NODES / 4, 256, 0, stream>>>(feat16, el, er, b0, offs, csr_src,
                                               out, h1, 0);

    // ---- layer 2 (reads h1 fp16; final head-major fp32 write to d_out)
    mfma_gemm<0><<<ggrid, 512, 0, stream>>>(h1, nullptr, wt1, al1, ar1, feat16, el, er);
    agg_fused<<<N_NODES / 4, 256, 0, stream>>>(feat16, el, er, b1, offs, csr_src,
                                               out, h1, 1);
}

// Round 7
// 381.496 us; speedup vs baseline: 2.4290x; 2.4290x over previous
//
#include <hip/hip_runtime.h>
#include <math.h>

#define N_NODES 50000
#define N_EDGES 800000
#define HEADS 4
#define HID 64
#define FDIM 256      // HEADS*HID == F_IN == 256 for both layers
#define LDA 40        // padded LDS k-stride (halves): 80B row stride
#define SCAN_CHUNK 1024
#define SCAN_NB ((N_NODES + SCAN_CHUNK - 1) / SCAN_CHUNK)   // 49

typedef __attribute__((ext_vector_type(8))) _Float16 half8;
typedef __attribute__((ext_vector_type(4))) _Float16 half4;
typedef __attribute__((ext_vector_type(4))) float f32x4;

// ---------------------------------------------------------------- CSR build
// NOTE (R6 lesson): do NOT fuse these with hipLaunchCooperativeKernel —
// grid.sync() across 1024 blocks costs ~100+us per sync on MI355X (8 XCDs,
// non-coherent L2s): measured 620us for the fused kernel vs ~60us separate.

__global__ __launch_bounds__(256) void hist_kernel(const int* __restrict__ dst,
                                                   int* __restrict__ counts, int E) {
    int i = blockIdx.x * blockDim.x + threadIdx.x;
    if (i < E) atomicAdd(&counts[dst[i]], 1);
}

__global__ __launch_bounds__(256) void scan_local(const int* __restrict__ counts,
                                                  int* __restrict__ offs,
                                                  int* __restrict__ bsum, int n) {
    __shared__ int part[256];
    const int b = blockIdx.x, t = threadIdx.x;
    const int base = b * SCAN_CHUNK + t * 4;
    int v[4];
#pragma unroll
    for (int j = 0; j < 4; j++) {
        int idx = base + j;
        v[j] = (idx < n) ? counts[idx] : 0;
    }
    int s0 = v[0], s1 = s0 + v[1], s2 = s1 + v[2], s3 = s2 + v[3];
    part[t] = s3;
    __syncthreads();
    for (int off = 1; off < 256; off <<= 1) {
        int x = (t >= off) ? part[t - off] : 0;
        __syncthreads();
        part[t] += x;
        __syncthreads();
    }
    int prefix = (t > 0) ? part[t - 1] : 0;
    int e[4] = {prefix, prefix + s0, prefix + s1, prefix + s2};
#pragma unroll
    for (int j = 0; j < 4; j++) {
        int idx = base + j;
        if (idx < n) offs[idx] = e[j];
    }
    if (t == 255) bsum[b] = part[255];
}

__global__ __launch_bounds__(64) void scan_bsum(int* __restrict__ bsum,
                                                int* __restrict__ offs, int nb, int n) {
    int lane = threadIdx.x;
    int own = (lane < nb) ? bsum[lane] : 0;
    int v = own;
    for (int off = 1; off < 64; off <<= 1) {
        int x = __shfl_up(v, off);
        if (lane >= off) v += x;
    }
    if (lane < nb) bsum[lane] = v - own;   // exclusive prefix
    if (lane == nb - 1) offs[n] = v;       // grand total
}

__global__ __launch_bounds__(256) void scan_add(int* __restrict__ offs,
                                                const int* __restrict__ bsum, int n) {
    const int b = blockIdx.x;
    const int p = bsum[b];
    const int base = b * SCAN_CHUNK + threadIdx.x * 4;
#pragma unroll
    for (int j = 0; j < 4; j++) {
        int idx = base + j;
        if (idx < n) offs[idx] += p;
    }
}

__global__ __launch_bounds__(256) void scatter_kernel(const int* __restrict__ src,
                                                      const int* __restrict__ dst,
                                                      const int* __restrict__ offs,
                                                      int* __restrict__ cursor,
                                                      int* __restrict__ csr_src, int E) {
    int i = blockIdx.x * blockDim.x + threadIdx.x;
    if (i < E) {
        int d = dst[i];
        int p = offs[d] + atomicAdd(&cursor[d], 1);
        csr_src[p] = src[i];
    }
}

// -------------------------------------------- prep: W transpose-cast

__global__ __launch_bounds__(256) void wcast_kernel(const float* __restrict__ W0,
                                                    const float* __restrict__ W1,
                                                    _Float16* __restrict__ wt0,
                                                    _Float16* __restrict__ wt1) {
    const float* W = blockIdx.y ? W1 : W0;
    _Float16* wt = blockIdx.y ? wt1 : wt0;
    int n = blockIdx.x * 16 + (threadIdx.x >> 4);
    int k0 = (threadIdx.x & 15) * 16;
    for (int j = 0; j < 16; j++)
        wt[n * FDIM + k0 + j] = (_Float16)W[(k0 + j) * FDIM + n];
}

// -------------------------------------------- fp16 MFMA GEMM + fused el/er
// v5: operand-SWAPPED mfma — acc[mt][nt] = mfma(bf[nt], af[mt], ...) puts
// the C fragment in transposed lane order: lane's l16 = m-row, quad*4+r =
// 4 CONSECUTIVE n-cols. Epilogue then does 16x half4 (8B) vector stores per
// thread (was 64x scalar 2B) and el/er via per-lane float4 FMA + 2 shuffles
// (was 32 shuffles per mt). Previous epilogue was the GEMM bottleneck:
// 12.8M scalar stores per dispatch.
// BN=256 (whole N per block), 512 threads / 8 waves, 64x64 per wave.
// Template A32: stage A directly from fp32 (layer 1 — no cast pass).
template <int A32>
__global__ __launch_bounds__(512) void mfma_gemm(const _Float16* __restrict__ A16,
                                                 const float* __restrict__ Af,
                                                 const _Float16* __restrict__ Bt,
                                                 const float* __restrict__ al,
                                                 const float* __restrict__ ar,
                                                 _Float16* __restrict__ feat16,
                                                 float* __restrict__ el,
                                                 float* __restrict__ er) {
    __shared__ _Float16 ash[128][LDA];
    __shared__ _Float16 bsh[256][LDA];

    const int t = threadIdx.x;
    const int m0 = blockIdx.x * 128;
    const int wave = t >> 6, lane = t & 63;
    const int quad = lane >> 4, l16 = lane & 15;
    const int wr = (wave >> 2) * 64;
    const int wc = (wave & 3) * 64;

    const f32x4 zero = {0.f, 0.f, 0.f, 0.f};
    f32x4 acc[4][4];
#pragma unroll
    for (int i = 0; i < 4; i++)
#pragma unroll
        for (int j = 0; j < 4; j++) acc[i][j] = zero;

    for (int kk = 0; kk < FDIM; kk += 32) {
        // ---- stage A: 128 rows x 32 halves = 512 x 8-half chunks, 1/thread
        {
            int row = t >> 2;
            int kb = (t & 3) * 8;
            int gr = m0 + row; if (gr >= N_NODES) gr = N_NODES - 1;
            if (A32) {
                const float* p = &Af[(size_t)gr * FDIM + kk + kb];
                float4 f0 = *(const float4*)p;
                float4 f1 = *(const float4*)(p + 4);
                half8 hv = {(_Float16)f0.x, (_Float16)f0.y, (_Float16)f0.z, (_Float16)f0.w,
                            (_Float16)f1.x, (_Float16)f1.y, (_Float16)f1.z, (_Float16)f1.w};
                *(half8*)&ash[row][kb] = hv;
            } else {
                *(half8*)&ash[row][kb] = *(const half8*)&A16[(size_t)gr * FDIM + kk + kb];
            }
        }
        // ---- stage B: 256 rows x 32 halves = 1024 chunks, 2/thread
#pragma unroll
        for (int ii = 0; ii < 2; ii++) {
            int idx = t + ii * 512;
            int row = idx >> 2;
            int kb = (idx & 3) * 8;
            *(half8*)&bsh[row][kb] = *(const half8*)&Bt[(size_t)row * FDIM + kk + kb];
        }
        __syncthreads();

        half8 af[4], bf[4];
#pragma unroll
        for (int i = 0; i < 4; i++) {
            af[i] = *(half8*)&ash[wr + i * 16 + l16][quad * 8];
            bf[i] = *(half8*)&bsh[wc + i * 16 + l16][quad * 8];
        }
        // swapped operands: C fragment transposed (l16 = m-row, quad*4+r = n-col)
#pragma unroll
        for (int mt = 0; mt < 4; mt++)
#pragma unroll
            for (int nt = 0; nt < 4; nt++)
                acc[mt][nt] = __builtin_amdgcn_mfma_f32_16x16x32_f16(bf[nt], af[mt], acc[mt][nt], 0, 0, 0);
        __syncthreads();
    }

    // ---- epilogue: vector feat16 store + fused el/er (this wave's head = h)
    const int h = wc >> 6;
    float4 alv[4], arv[4];
#pragma unroll
    for (int nt = 0; nt < 4; nt++) {
        alv[nt] = *(const float4*)&al[wc + nt * 16 + quad * 4];
        arv[nt] = *(const float4*)&ar[wc + nt * 16 + quad * 4];
    }
#pragma unroll
    for (int mt = 0; mt < 4; mt++) {
        const int m = m0 + wr + mt * 16 + l16;
        const bool ok = (m < N_NODES);
        float pl = 0.f, pr = 0.f;
#pragma unroll
        for (int nt = 0; nt < 4; nt++) {
            f32x4 v = acc[mt][nt];
            if (ok) {
                half4 hv = {(_Float16)v[0], (_Float16)v[1], (_Float16)v[2], (_Float16)v[3]};
                *(half4*)&feat16[(size_t)m * FDIM + wc + nt * 16 + quad * 4] = hv;
            }
            pl += v[0] * alv[nt].x + v[1] * alv[nt].y + v[2] * alv[nt].z + v[3] * alv[nt].w;
            pr += v[0] * arv[nt].x + v[1] * arv[nt].y + v[2] * arv[nt].z + v[3] * arv[nt].w;
        }
        // reduce over the 4 quads (lanes l16, l16+16, l16+32, l16+48)
        pl += __shfl_xor(pl, 16);
        pl += __shfl_xor(pl, 32);
        pr += __shfl_xor(pr, 16);
        pr += __shfl_xor(pr, 32);
        if (quad == 0 && ok) {
            el[m * 4 + h] = pl;
            er[m * 4 + h] = pr;
        }
    }
}

// ------------------------------------------- fused softmax + aggregate
// Wave per node, NO LDS / NO barriers. Lane owns features f=lane*4..+3
// (head = lane>>4).
//
// v2 (best measured; traffic-bound at ~3.9 TB/s beyond-L2, invariant to
// scheduling — v3's deeper MLP regressed): cooperative weights. Edges
// walked in 16-chunks; W-phase: lane (lane&15)==j computes edge c+j's
// weight for its OWN head; MAC-phase broadcasts (s,w) via __shfl, 4-wide.
// Denominator accumulated per-lane, reduced once at the end.
// Single-pass softmax (no max subtraction — logits are O(1)).
// mode 0: write h1 as fp16 (layer-2 GEMM input, lives in d_out)
// mode 1: final fp32 head-major write
__global__ __launch_bounds__(256) void agg_fused(const _Float16* __restrict__ feat16,
                                                 const float* __restrict__ el,
                                                 const float* __restrict__ er,
                                                 const float* __restrict__ bias,
                                                 const int* __restrict__ offs,
                                                 const int* __restrict__ csr_src,
                                                 float* __restrict__ out,
                                                 _Float16* __restrict__ h1,
                                                 int mode) {
    const int wave = threadIdx.x >> 6;
    const int lane = threadIdx.x & 63;
    const int n = blockIdx.x * 4 + wave;
    const int head = lane >> 4;
    const int f = lane * 4;           // == head*64 + (lane&15)*4
    const int base16 = lane & 48;     // first lane of this head's 16-group
    const int j16 = lane & 15;
    const int beg = offs[n];
    const int end = offs[n + 1];
    const float er_h = er[n * 4 + head];

    float4 acc = make_float4(0.f, 0.f, 0.f, 0.f);
    float ss = 0.f;

    for (int c = beg; c < end; c += 16) {
        // ---- W-phase: this lane owns edge c + j16 (for its own head)
        int e = c + j16;
        int s_own = 0;
        float w_own = 0.f;
        if (e < end) {
            s_own = csr_src[e];
            float lg = el[s_own * 4 + head] + er_h;
            lg = (lg > 0.f) ? lg : 0.2f * lg;
            w_own = __expf(lg);
        }
        ss += w_own;

        int rem = end - c;
        if (rem > 16) rem = 16;

        // ---- MAC-phase: walk the chunk's edges, s/w via shuffle broadcast
        int j = 0;
        for (; j + 3 < rem; j += 4) {
            int s0 = __shfl(s_own, base16 + j);
            int s1 = __shfl(s_own, base16 + j + 1);
            int s2 = __shfl(s_own, base16 + j + 2);
            int s3 = __shfl(s_own, base16 + j + 3);
            float w0 = __shfl(w_own, base16 + j);
            float w1 = __shfl(w_own, base16 + j + 1);
            float w2 = __shfl(w_own, base16 + j + 2);
            float w3 = __shfl(w_own, base16 + j + 3);
            half4 v0 = *(const half4*)&feat16[(size_t)s0 * FDIM + f];
            half4 v1 = *(const half4*)&feat16[(size_t)s1 * FDIM + f];
            half4 v2 = *(const half4*)&feat16[(size_t)s2 * FDIM + f];
            half4 v3 = *(const half4*)&feat16[(size_t)s3 * FDIM + f];
            acc.x += w0 * (float)v0[0] + w1 * (float)v1[0];
            acc.y += w0 * (float)v0[1] + w1 * (float)v1[1];
            acc.z += w0 * (float)v0[2] + w1 * (float)v1[2];
            acc.w += w0 * (float)v0[3] + w1 * (float)v1[3];
            acc.x += w2 * (float)v2[0] + w3 * (float)v3[0];
            acc.y += w2 * (float)v2[1] + w3 * (float)v3[1];
            acc.z += w2 * (float)v2[2] + w3 * (float)v3[2];
            acc.w += w2 * (float)v2[3] + w3 * (float)v3[3];
        }
        for (; j < rem; j++) {
            int s0 = __shfl(s_own, base16 + j);
            float w0 = __shfl(w_own, base16 + j);
            half4 v0 = *(const half4*)&feat16[(size_t)s0 * FDIM + f];
            acc.x += w0 * (float)v0[0];
            acc.y += w0 * (float)v0[1];
            acc.z += w0 * (float)v0[2];
            acc.w += w0 * (float)v0[3];
        }
    }

    // ---- reduce softmax denominator across the 16-lane head group
    ss += __shfl_xor(ss, 1, 16);
    ss += __shfl_xor(ss, 2, 16);
    ss += __shfl_xor(ss, 4, 16);
    ss += __shfl_xor(ss, 8, 16);

    float S = fmaxf(ss, 1e-9f);
    float inv = 1.f / S;
    float4 bv = *(const float4*)&bias[f];
    float r0 = acc.x * inv + bv.x;
    float r1 = acc.y * inv + bv.y;
    float r2 = acc.z * inv + bv.z;
    float r3 = acc.w * inv + bv.w;
    r0 = (r0 > 0.f) ? r0 : expm1f(r0);
    r1 = (r1 > 0.f) ? r1 : expm1f(r1);
    r2 = (r2 > 0.f) ? r2 : expm1f(r2);
    r3 = (r3 > 0.f) ? r3 : expm1f(r3);

    if (mode) {
        const int d = (lane & 15) * 4;
        float4 rv = make_float4(r0, r1, r2, r3);
        *(float4*)&out[(size_t)head * N_NODES * HID + (size_t)n * HID + d] = rv;
    } else {
        half4 hv = {(_Float16)r0, (_Float16)r1, (_Float16)r2, (_Float16)r3};
        *(half4*)&h1[(size_t)n * FDIM + f] = hv;
    }
}

// ---------------------------------------------------------------- launch

extern "C" void kernel_launch(void* const* d_in, const int* in_sizes, int n_in,
                              void* d_out, int out_size, void* d_ws, size_t ws_size,
                              hipStream_t stream) {
    const float* x   = (const float*)d_in[0];
    const int*   src = (const int*)d_in[1];
    const int*   dst = (const int*)d_in[2];
    const float* W0  = (const float*)d_in[3];
    const float* al0 = (const float*)d_in[4];
    const float* ar0 = (const float*)d_in[5];
    const float* b0  = (const float*)d_in[6];
    const float* W1  = (const float*)d_in[7];
    const float* al1 = (const float*)d_in[8];
    const float* ar1 = (const float*)d_in[9];
    const float* b1  = (const float*)d_in[10];
    float* out = (float*)d_out;

    // h1 (layer-1 hidden, fp16) lives in the first 25.6 MB of d_out.
    // Timeline: gemm-1 reads x fp32 directly -> agg(mode0) writes h1 ->
    // gemm-2 reads h1 -> agg(mode1) overwrites all of d_out with the final
    // output. All sequential on stream.
    _Float16* h1 = (_Float16*)d_out;

    // workspace layout
    _Float16* feat16 = (_Float16*)d_ws;                          // N*256 fp16
    _Float16* wt0 = feat16 + (size_t)N_NODES * FDIM;             // 256*256
    _Float16* wt1 = wt0 + FDIM * FDIM;                           // 256*256
    float* el    = (float*)(wt1 + FDIM * FDIM);                  // N*4
    float* er    = el + N_NODES * HEADS;                         // N*4
    int* counts  = (int*)(er + N_NODES * HEADS);                 // N
    int* cursor  = counts + N_NODES;                             // N
    int* offs    = cursor + N_NODES;                             // N+1 (pad 50016)
    int* bsum    = offs + 50016;                                 // 64
    int* csr_src = bsum + 64;                                    // E

    // ---- prep + CSR build
    hipMemsetAsync(counts, 0, 2 * N_NODES * sizeof(int), stream);  // counts + cursor
    wcast_kernel<<<dim3(16, 2), 256, 0, stream>>>(W0, W1, wt0, wt1);
    hist_kernel<<<(N_EDGES + 255) / 256, 256, 0, stream>>>(dst, counts, N_EDGES);
    scan_local<<<SCAN_NB, 256, 0, stream>>>(counts, offs, bsum, N_NODES);
    scan_bsum<<<1, 64, 0, stream>>>(bsum, offs, SCAN_NB, N_NODES);
    scan_add<<<SCAN_NB, 256, 0, stream>>>(offs, bsum, N_NODES);
    scatter_kernel<<<(N_EDGES + 255) / 256, 256, 0, stream>>>(src, dst, offs, cursor, csr_src, N_EDGES);

    const int ggrid = (N_NODES + 127) / 128;   // 391

    // ---- layer 1 (A from fp32 x; h1 fp16 written into d_out)
    mfma_gemm<1><<<ggrid, 512, 0, stream>>>(nullptr, x, wt0, al0, ar0, feat16, el, er);
    agg_fused<<<N_NODES / 4, 256, 0, stream>>>(feat16, el, er, b0, offs, csr_src,
                                               out, h1, 0);

    // ---- layer 2 (reads h1 fp16; final head-major fp32 write to d_out)
    mfma_gemm<0><<<ggrid, 512, 0, stream>>>(h1, nullptr, wt1, al1, ar1, feat16, el, er);
    agg_fused<<<N_NODES / 4, 256, 0, stream>>>(feat16, el, er, b1, offs, csr_src,
                                               out, h1, 1);
}